// Round 2
// baseline (349.627 us; speedup 1.0000x reference)
//
#include <hip/hip_runtime.h>
#include <hip/hip_bf16.h>

#define NOPT    5
#define NBATCH  100000
#define MTOT    (NOPT * NBATCH)   // 500000 rows
#define KDIM    600
#define NKS     19                // k-steps of 32 (last overlaps: k=568..599)
#define NT      5                 // n-tiles of 16 (75 -> 80, tail zero-padded)

typedef __bf16 bf16x8 __attribute__((ext_vector_type(8)));
typedef float  f32x4  __attribute__((ext_vector_type(4)));

__device__ __forceinline__ int kstart(int s) { return (s < 18) ? (s << 5) : 568; }

// Pre-transform W1 [75][600] fp32 -> bf16 image in exact MFMA B-fragment order:
// img[(s*5+t)*512 + l*8 + j] = W1[n=t*16+(l&15)][k=kstart(s)+(l>>4)*8+j], zeros for
// n>=75 and for the duplicated k range of the overlapping tail tile (s==18, kg==0).
__global__ void prep_w1(const float* __restrict__ W1, __bf16* __restrict__ img) {
    const int s  = blockIdx.x / NT;
    const int t  = blockIdx.x % NT;
    const int l  = threadIdx.x;            // 0..63
    const int kg = l >> 4;
    const int n  = t * 16 + (l & 15);
    const int ks = kstart(s);
    bf16x8 v;
#pragma unroll
    for (int j = 0; j < 8; ++j) {
        const int k = ks + kg * 8 + j;
        float f = 0.0f;
        if (n < 75 && !(s == 18 && kg == 0)) f = W1[n * KDIM + k];
        v[j] = (__bf16)f;
    }
    *(bf16x8*)(img + ((size_t)blockIdx.x * 64 + l) * 8) = v;
}

// LDS-free: each wave owns 16 rows, fully independent (no __syncthreads).
// Register double-buffer (named ping-pong regs), loads of step s+1 issued
// before compute of step s; compiler counts vmcnt for us.
__global__ void __launch_bounds__(256) ans_sel_kernel(
    const float* __restrict__ A,     // [500000][600] fp32
    const float* __restrict__ b1,    // [75]
    const float* __restrict__ W2,    // [75]
    const float* __restrict__ b2,    // [1]
    const __bf16* __restrict__ img,  // prepped W1 fragments
    float* __restrict__ out)         // [100000][5]
{
    const int tid  = threadIdx.x;
    const int w    = tid >> 6;
    const int l    = tid & 63;
    const int kg   = l >> 4;
    const int ln16 = l & 15;
    const int rowbase = blockIdx.x * 64 + w * 16;

    int gr = rowbase + ln16; if (gr >= MTOT) gr = MTOT - 1;
    const float*  ap = A + (size_t)gr * KDIM + kg * 8;  // lane's 8-k slot
    const __bf16* bp = img + (size_t)l * 8;

    f32x4 acc[NT];
#pragma unroll
    for (int t = 0; t < NT; ++t) acc[t] = (f32x4){0.f, 0.f, 0.f, 0.f};

    auto LDA = [&](int s, f32x4& x0, f32x4& x1) {
        const float* p = ap + kstart(s);
        x0 = *(const f32x4*)(p);
        x1 = *(const f32x4*)(p + 4);
    };
    auto LDB = [&](int s, bf16x8& b0v, bf16x8& b1v, bf16x8& b2v, bf16x8& b3v, bf16x8& b4v) {
        const __bf16* p = bp + (size_t)s * (NT * 512);
        b0v = *(const bf16x8*)(p);
        b1v = *(const bf16x8*)(p + 512);
        b2v = *(const bf16x8*)(p + 1024);
        b3v = *(const bf16x8*)(p + 1536);
        b4v = *(const bf16x8*)(p + 2048);
    };
    auto CMP = [&](f32x4 x0, f32x4 x1, bf16x8 b0v, bf16x8 b1v, bf16x8 b2v, bf16x8 b3v, bf16x8 b4v) {
        bf16x8 a;
        a[0] = (__bf16)x0[0]; a[1] = (__bf16)x0[1];
        a[2] = (__bf16)x0[2]; a[3] = (__bf16)x0[3];
        a[4] = (__bf16)x1[0]; a[5] = (__bf16)x1[1];
        a[6] = (__bf16)x1[2]; a[7] = (__bf16)x1[3];
        acc[0] = __builtin_amdgcn_mfma_f32_16x16x32_bf16(a, b0v, acc[0], 0, 0, 0);
        acc[1] = __builtin_amdgcn_mfma_f32_16x16x32_bf16(a, b1v, acc[1], 0, 0, 0);
        acc[2] = __builtin_amdgcn_mfma_f32_16x16x32_bf16(a, b2v, acc[2], 0, 0, 0);
        acc[3] = __builtin_amdgcn_mfma_f32_16x16x32_bf16(a, b3v, acc[3], 0, 0, 0);
        acc[4] = __builtin_amdgcn_mfma_f32_16x16x32_bf16(a, b4v, acc[4], 0, 0, 0);
    };

    f32x4 ca0, ca1, na0, na1;
    bf16x8 cb0, cb1, cb2, cb3, cb4, nb0, nb1, nb2, nb3, nb4;

    LDA(0, ca0, ca1);
    LDB(0, cb0, cb1, cb2, cb3, cb4);
#pragma unroll 2
    for (int s = 0; s < NKS - 1; ++s) {
        LDA(s + 1, na0, na1);
        LDB(s + 1, nb0, nb1, nb2, nb3, nb4);
        CMP(ca0, ca1, cb0, cb1, cb2, cb3, cb4);
        ca0 = na0; ca1 = na1;
        cb0 = nb0; cb1 = nb1; cb2 = nb2; cb3 = nb3; cb4 = nb4;
    }
    CMP(ca0, ca1, cb0, cb1, cb2, cb3, cb4);

    // Epilogue: C[row=(kg*4+q)][n=t*16+ln16] per lane (verified m89/m91 layout).
    float sq[4] = {0.f, 0.f, 0.f, 0.f};
#pragma unroll
    for (int t = 0; t < NT; ++t) {
        const int n = t * 16 + ln16;
        const float b1v = (n < 75) ? b1[n] : 0.f;
        const float w2v = (n < 75) ? W2[n] : 0.f;
#pragma unroll
        for (int q = 0; q < 4; ++q) {
            float h = acc[t][q] + b1v;
            h = h > 0.f ? h : 0.f;
            sq[q] += h * w2v;
        }
    }
#pragma unroll
    for (int m = 1; m < 16; m <<= 1) {
#pragma unroll
        for (int q = 0; q < 4; ++q) sq[q] += __shfl_xor(sq[q], m, 64);
    }
    if (ln16 == 0) {
        const float bb = b2[0];
#pragma unroll
        for (int q = 0; q < 4; ++q) {
            const int R = rowbase + kg * 4 + q;      // global row = o*NBATCH + b
            if (R < MTOT) {
                const int o = R / NBATCH;
                const int b = R % NBATCH;
                out[(size_t)b * NOPT + o] = sq[q] + bb;
            }
        }
    }
}

extern "C" void kernel_launch(void* const* d_in, const int* in_sizes, int n_in,
                              void* d_out, int out_size, void* d_ws, size_t ws_size,
                              hipStream_t stream) {
    const float* A  = (const float*)d_in[0];
    const float* W1 = (const float*)d_in[1];
    const float* b1 = (const float*)d_in[2];
    const float* W2 = (const float*)d_in[3];
    const float* b2 = (const float*)d_in[4];
    float* out = (float*)d_out;
    __bf16* img = (__bf16*)d_ws;     // needs 19*5*64*8*2 = 97280 B

    prep_w1<<<NKS * NT, 64, 0, stream>>>(W1, img);

    const int grid = (MTOT + 63) / 64;   // 7813 blocks, 4 independent waves each
    ans_sel_kernel<<<grid, 256, 0, stream>>>(A, b1, W2, b2, img, out);
}

// Round 4
// 341.001 us; speedup vs baseline: 1.0253x; 1.0253x over previous
//
#include <hip/hip_runtime.h>
#include <hip/hip_bf16.h>

#define NOPT    5
#define NBATCH  100000
#define MTOT    (NOPT * NBATCH)   // 500000 rows
#define KDIM    600
#define NKS     19                // k-steps of 32 (last overlaps: k=568..599)
#define NT      5                 // n-tiles of 16 (75 -> 80, tail zero-padded)

typedef __bf16 bf16x8 __attribute__((ext_vector_type(8)));
typedef float  f32x4  __attribute__((ext_vector_type(4)));

__device__ __forceinline__ int kstart(int s) { return (s < 18) ? (s << 5) : 568; }

// Pre-transform W1 [75][600] fp32 -> bf16 image in exact MFMA B-fragment order:
// img[(s*5+t)*512 + l*8 + j] = W1[n=t*16+(l&15)][k=kstart(s)+(l>>4)*8+j], zeros for
// n>=75 and for the duplicated k range of the overlapping tail tile (s==18, kg==0).
__global__ void prep_w1(const float* __restrict__ W1, __bf16* __restrict__ img) {
    const int s  = blockIdx.x / NT;
    const int t  = blockIdx.x % NT;
    const int l  = threadIdx.x;            // 0..63
    const int kg = l >> 4;
    const int n  = t * 16 + (l & 15);
    const int ks = kstart(s);
    bf16x8 v;
#pragma unroll
    for (int j = 0; j < 8; ++j) {
        const int k = ks + kg * 8 + j;
        float f = 0.0f;
        if (n < 75 && !(s == 18 && kg == 0)) f = W1[n * KDIM + k];
        v[j] = (__bf16)f;
    }
    *(bf16x8*)(img + ((size_t)blockIdx.x * 64 + l) * 8) = v;
}

// Barrier-free T14 reg-staging: each wave is fully independent (it only ever
// reads the LDS rows it wrote itself). Per iteration: issue A/B loads of s+1
// early (global->reg, compiler-tracked vmcnt), compute tile s from LDS + B
// regs, then ds_write the A regs into buf[(s+1)&1] (write-late; the compiler
// emits a counted vmcnt wait for just the A regs, leaving B in flight).
__global__ void __launch_bounds__(256, 4) ans_sel_kernel(
    const float* __restrict__ A,     // [500000][600] fp32
    const float* __restrict__ b1,    // [75]
    const float* __restrict__ W2,    // [75]
    const float* __restrict__ b2,    // [1]
    const __bf16* __restrict__ img,  // prepped W1 fragments
    float* __restrict__ out)         // [100000][5]
{
    __shared__ f32x4 As[2][512];     // 2 bufs x [64 rows][8 chunks of 16B] = 16 KB

    const int tid  = threadIdx.x;
    const int w    = tid >> 6;       // wave 0..3
    const int l    = tid & 63;
    const int kg   = l >> 4;
    const int ln16 = l & 15;
    const int row0 = blockIdx.x * 64;

    // --- A load geometry: lane l loads 16B of row r0 = w*16 + (l>>3), chunk
    // pch = l&7 (8 lanes cover one row's 128B span contiguously), and the
    // same chunk of row r0+8. Proven-coalesced shape from round 1.
    const int lr  = l >> 3;
    const int pch = l & 7;
    const int r0  = w * 16 + lr;
    const int r1  = r0 + 8;
    int g0 = row0 + r0; if (g0 >= MTOT) g0 = MTOT - 1;
    int g1 = row0 + r1; if (g1 >= MTOT) g1 = MTOT - 1;
    const float* ap0 = A + (size_t)g0 * KDIM + pch * 4;
    const float* ap1 = A + (size_t)g1 * KDIM + pch * 4;

    // --- LDS write slots (XOR chunk swizzle; note (r0&7) == (r1&7) == lr)
    f32x4* const wp0 = &As[0][r0 * 8 + (pch ^ lr)];
    f32x4* const wp1 = &As[0][r1 * 8 + (pch ^ lr)];

    const __bf16* bp = img + (size_t)l * 8;

    f32x4 acc[NT];
#pragma unroll
    for (int t = 0; t < NT; ++t) acc[t] = (f32x4){0.f, 0.f, 0.f, 0.f};

    auto LDB = [&](int s, bf16x8& v0, bf16x8& v1, bf16x8& v2, bf16x8& v3, bf16x8& v4) {
        const __bf16* p = bp + (size_t)s * (NT * 512);
        v0 = *(const bf16x8*)(p);
        v1 = *(const bf16x8*)(p + 512);
        v2 = *(const bf16x8*)(p + 1024);
        v3 = *(const bf16x8*)(p + 1536);
        v4 = *(const bf16x8*)(p + 2048);
    };

    auto compute = [&](int buf, bf16x8 v0, bf16x8 v1, bf16x8 v2, bf16x8 v3, bf16x8 v4) {
        const f32x4* base = &As[buf][(w * 16 + ln16) * 8];
        const int x = ln16 & 7;
        f32x4 fa0 = base[(kg * 2)     ^ x];
        f32x4 fa1 = base[(kg * 2 + 1) ^ x];
        bf16x8 a;
        a[0] = (__bf16)fa0[0]; a[1] = (__bf16)fa0[1];
        a[2] = (__bf16)fa0[2]; a[3] = (__bf16)fa0[3];
        a[4] = (__bf16)fa1[0]; a[5] = (__bf16)fa1[1];
        a[6] = (__bf16)fa1[2]; a[7] = (__bf16)fa1[3];
        acc[0] = __builtin_amdgcn_mfma_f32_16x16x32_bf16(a, v0, acc[0], 0, 0, 0);
        acc[1] = __builtin_amdgcn_mfma_f32_16x16x32_bf16(a, v1, acc[1], 0, 0, 0);
        acc[2] = __builtin_amdgcn_mfma_f32_16x16x32_bf16(a, v2, acc[2], 0, 0, 0);
        acc[3] = __builtin_amdgcn_mfma_f32_16x16x32_bf16(a, v3, acc[3], 0, 0, 0);
        acc[4] = __builtin_amdgcn_mfma_f32_16x16x32_bf16(a, v4, acc[4], 0, 0, 0);
    };

    bf16x8 cb0, cb1, cb2, cb3, cb4, nb0, nb1, nb2, nb3, nb4;
    f32x4 ra0, ra1;

    // Prologue: tile 0 -> regs -> LDS buf0; B(0) -> regs.
    ra0 = *(const f32x4*)(ap0 + kstart(0));
    ra1 = *(const f32x4*)(ap1 + kstart(0));
    LDB(0, cb0, cb1, cb2, cb3, cb4);
    wp0[0] = ra0;              // compiler waits (counted) for ra0/ra1 here
    wp1[0] = ra1;

#pragma unroll 2
    for (int s = 0; s < NKS - 1; ++s) {
        // issue-early: loads for tile s+1
        ra0 = *(const f32x4*)(ap0 + kstart(s + 1));
        ra1 = *(const f32x4*)(ap1 + kstart(s + 1));
        LDB(s + 1, nb0, nb1, nb2, nb3, nb4);
        // compute current tile (ds_read + MFMA; B(s) already resident)
        compute(s & 1, cb0, cb1, cb2, cb3, cb4);
        // write-late: stage tile s+1 into the other buffer
        const int nbuf = (s + 1) & 1;
        wp0[nbuf * 512] = ra0;
        wp1[nbuf * 512] = ra1;
        cb0 = nb0; cb1 = nb1; cb2 = nb2; cb3 = nb3; cb4 = nb4;
    }
    compute((NKS - 1) & 1, cb0, cb1, cb2, cb3, cb4);

    // Epilogue: C[row=(kg*4+q)][n=t*16+ln16] per lane (verified m89/m91 layout).
    float sq[4] = {0.f, 0.f, 0.f, 0.f};
#pragma unroll
    for (int t = 0; t < NT; ++t) {
        const int n = t * 16 + ln16;
        const float b1v = (n < 75) ? b1[n] : 0.f;
        const float w2v = (n < 75) ? W2[n] : 0.f;
#pragma unroll
        for (int q = 0; q < 4; ++q) {
            float h = acc[t][q] + b1v;
            h = h > 0.f ? h : 0.f;
            sq[q] += h * w2v;
        }
    }
#pragma unroll
    for (int m = 1; m < 16; m <<= 1) {
#pragma unroll
        for (int q = 0; q < 4; ++q) sq[q] += __shfl_xor(sq[q], m, 64);
    }
    if (ln16 == 0) {
        const float bb = b2[0];
#pragma unroll
        for (int q = 0; q < 4; ++q) {
            const int R = row0 + w * 16 + kg * 4 + q;   // global row = o*NBATCH + b
            if (R < MTOT) {
                const int o = R / NBATCH;
                const int b = R % NBATCH;
                out[(size_t)b * NOPT + o] = sq[q] + bb;
            }
        }
    }
}

extern "C" void kernel_launch(void* const* d_in, const int* in_sizes, int n_in,
                              void* d_out, int out_size, void* d_ws, size_t ws_size,
                              hipStream_t stream) {
    const float* A  = (const float*)d_in[0];
    const float* W1 = (const float*)d_in[1];
    const float* b1 = (const float*)d_in[2];
    const float* W2 = (const float*)d_in[3];
    const float* b2 = (const float*)d_in[4];
    float* out = (float*)d_out;
    __bf16* img = (__bf16*)d_ws;     // needs 19*5*64*8*2 = 97280 B

    prep_w1<<<NKS * NT, 64, 0, stream>>>(W1, img);

    const int grid = (MTOT + 63) / 64;   // 7813 blocks, 4 independent waves each
    ans_sel_kernel<<<grid, 256, 0, stream>>>(A, b1, W2, b2, img, out);
}